// Round 2
// baseline (969.019 us; speedup 1.0000x reference)
//
#include <hip/hip_runtime.h>
#include <hip/hip_bf16.h>
#include <math.h>

#define N_ATOMS 8192
#define N_EDGES 262144
#define N_MOL   128
#define FDIM    128
#define RDIM    20
#define LLAYERS 3
#define CUTOFF  5.0f
#define EPSV    1e-8f
#define PI_F    3.14159265358979323846f

// ---------------- embed gather ----------------
__global__ void k_embed(const int* __restrict__ z, const float* __restrict__ embed,
                        float* __restrict__ S) {
    int i = blockIdx.x * 256 + threadIdx.x;           // over 8192*128
    int a = i >> 7, k = i & 127;
    S[i] = embed[(size_t)z[a] * FDIM + k];
}

// ---------------- edge geometry + rbf ----------------
__global__ void k_edges(const float* __restrict__ pos, const int* __restrict__ esrc,
                        const int* __restrict__ edst, float* __restrict__ RBF,
                        float* __restrict__ FC, float* __restrict__ UNIT) {
    int e = blockIdx.x * 256 + threadIdx.x;
    if (e >= N_EDGES) return;
    int s = esrc[e], d = edst[e];
    float rx = pos[d*3+0] - pos[s*3+0];
    float ry = pos[d*3+1] - pos[s*3+1];
    float rz = pos[d*3+2] - pos[s*3+2];
    float dd = sqrtf(rx*rx + ry*ry + rz*rz + EPSV);
    float inv = 1.0f / dd;
    UNIT[(size_t)e*3+0] = rx * inv;
    UNIT[(size_t)e*3+1] = ry * inv;
    UNIT[(size_t)e*3+2] = rz * inv;
    FC[e] = (dd < CUTOFF) ? 0.5f * (cosf(dd * (PI_F / CUTOFF)) + 1.0f) : 0.0f;
    #pragma unroll
    for (int r = 0; r < RDIM; r++) {
        float freq = (float)(r + 1) * (PI_F / CUTOFF);
        RBF[(size_t)e*RDIM + r] = sinf(dd * freq) * inv;
    }
}

// ---------------- CSR build ----------------
__global__ void k_hist(const int* __restrict__ edst, int* __restrict__ CNT) {
    int e = blockIdx.x * 256 + threadIdx.x;
    if (e < N_EDGES) atomicAdd(&CNT[edst[e]], 1);
}

__global__ __launch_bounds__(1024) void k_scan(const int* __restrict__ CNT,
                                               int* __restrict__ OFF, int* __restrict__ CUR) {
    __shared__ int part[1024];
    int t = threadIdx.x;
    int loc[8];
    int run = 0;
    #pragma unroll
    for (int i = 0; i < 8; i++) { int c = CNT[t*8 + i]; loc[i] = run; run += c; }
    part[t] = run;
    __syncthreads();
    for (int off = 1; off < 1024; off <<= 1) {
        int v = 0;
        if (t >= off) v = part[t - off];
        __syncthreads();
        part[t] += v;
        __syncthreads();
    }
    int ebase = (t > 0) ? part[t-1] : 0;
    #pragma unroll
    for (int i = 0; i < 8; i++) { int o = ebase + loc[i]; OFF[t*8+i] = o; CUR[t*8+i] = o; }
    if (t == 1023) OFF[8192] = part[1023];
}

__global__ void k_fill(const int* __restrict__ edst, int* __restrict__ CUR,
                       int* __restrict__ EIDX) {
    int e = blockIdx.x * 256 + threadIdx.x;
    if (e < N_EDGES) {
        int p = atomicAdd(&CUR[edst[e]], 1);
        EIDX[p] = e;
    }
}

// ---------------- generic tiled f32 GEMM: C = act(A@B + bias) ----------------
// A is (M, K) row-major via [A | A2] split at column `split`; B is (K, N) row-major.
template <bool SILU>
__global__ __launch_bounds__(256) void k_gemm(
    const float* __restrict__ A, int lda, const float* __restrict__ A2, int lda2, int split,
    const float* __restrict__ B, const float* __restrict__ bias,
    float* __restrict__ C, int M, int N, int K)
{
    __shared__ float As[16][64];
    __shared__ float Bs[16][64];
    int bm = blockIdx.y * 64, bn = blockIdx.x * 64;
    int tid = threadIdx.x;
    int tx = tid & 15, ty = tid >> 4;
    float acc[4][4] = {{0.f}};
    int row = tid >> 2, kq = (tid & 3) * 4;
    int col = tid & 63, kr = tid >> 6;
    for (int k0 = 0; k0 < K; k0 += 16) {
        const float* Ablk; int ldab, kloc;
        if (k0 < split) { Ablk = A;  ldab = lda;  kloc = k0 + kq; }
        else            { Ablk = A2; ldab = lda2; kloc = k0 - split + kq; }
        float4 av = *(const float4*)&Ablk[(size_t)(bm + row) * ldab + kloc];
        As[kq+0][row] = av.x; As[kq+1][row] = av.y; As[kq+2][row] = av.z; As[kq+3][row] = av.w;
        #pragma unroll
        for (int i = 0; i < 4; i++)
            Bs[kr + 4*i][col] = B[(size_t)(k0 + kr + 4*i) * N + bn + col];
        __syncthreads();
        #pragma unroll
        for (int kk = 0; kk < 16; kk++) {
            float4 a4 = *(const float4*)&As[kk][ty*4];
            float4 b4 = *(const float4*)&Bs[kk][tx*4];
            float ar[4] = {a4.x, a4.y, a4.z, a4.w};
            float br[4] = {b4.x, b4.y, b4.z, b4.w};
            #pragma unroll
            for (int i = 0; i < 4; i++)
                #pragma unroll
                for (int j = 0; j < 4; j++)
                    acc[i][j] += ar[i] * br[j];
        }
        __syncthreads();
    }
    #pragma unroll
    for (int i = 0; i < 4; i++) {
        int m = bm + ty*4 + i;
        float4 o;
        float* op = &o.x;
        #pragma unroll
        for (int j = 0; j < 4; j++) {
            int n = bn + tx*4 + j;
            float val = acc[i][j] + (bias ? bias[n] : 0.0f);
            if (SILU) val = val / (1.0f + __expf(-val));
            op[j] = val;
        }
        *(float4*)&C[(size_t)m * N + bn + tx*4] = o;
    }
}

// ---------------- edge aggregation (gather form, one block per dst atom) ----------------
__global__ __launch_bounds__(128) void k_aggregate(
    const float* __restrict__ PHI, const float* __restrict__ vin,
    float* __restrict__ S, float* __restrict__ vout,
    const float* __restrict__ RBF, const float* __restrict__ FC, const float* __restrict__ UNIT,
    const int* __restrict__ esrc, const int* __restrict__ OFF, const int* __restrict__ EIDX,
    const float* __restrict__ rbfw, const float* __restrict__ rbfb)
{
    int a = blockIdx.x, t = threadIdx.x;
    float w0[RDIM], w1[RDIM], w2[RDIM];
    #pragma unroll
    for (int r = 0; r < RDIM; r++) {
        w0[r] = rbfw[r*384 + t];
        w1[r] = rbfw[r*384 + 128 + t];
        w2[r] = rbfw[r*384 + 256 + t];
    }
    float b0 = rbfb[t], b1 = rbfb[128 + t], b2 = rbfb[256 + t];
    int beg = OFF[a], end = OFF[a + 1];
    float accs = 0.f, av0 = 0.f, av1 = 0.f, av2 = 0.f;
    for (int p = beg; p < end; p++) {
        int e = EIDX[p];
        int src = esrc[e];
        float rb[RDIM];
        const float4* rb4 = (const float4*)&RBF[(size_t)e * RDIM];
        #pragma unroll
        for (int q = 0; q < 5; q++) {
            float4 v4 = rb4[q];
            rb[q*4+0] = v4.x; rb[q*4+1] = v4.y; rb[q*4+2] = v4.z; rb[q*4+3] = v4.w;
        }
        float fce = FC[e];
        float u0 = UNIT[(size_t)e*3+0], u1 = UNIT[(size_t)e*3+1], u2 = UNIT[(size_t)e*3+2];
        float f0 = b0, f1 = b1, f2 = b2;
        #pragma unroll
        for (int r = 0; r < RDIM; r++) {
            f0 += rb[r] * w0[r];
            f1 += rb[r] * w1[r];
            f2 += rb[r] * w2[r];
        }
        f0 *= fce; f1 *= fce; f2 *= fce;
        const float* ph = &PHI[(size_t)src * 384];
        float m0 = ph[t] * f0, m1 = ph[128 + t] * f1, m2 = ph[256 + t] * f2;
        const float* vs = &vin[(size_t)src * 384];
        accs += m0;
        av0 += vs[t]       * m1 + u0 * m2;
        av1 += vs[128 + t] * m1 + u1 * m2;
        av2 += vs[256 + t] * m1 + u2 * m2;
    }
    size_t sb = (size_t)a * 128 + t, vb = (size_t)a * 384 + t;
    S[sb] += accs;
    vout[vb]       = vin[vb]       + av0;
    vout[vb + 128] = vin[vb + 128] + av1;
    vout[vb + 256] = vin[vb + 256] + av2;
}

// ---------------- vv-norm + <uv,vv> ----------------
__global__ void k_vvdot(const float* __restrict__ UV, const float* __restrict__ VV,
                        float* __restrict__ VVN, float* __restrict__ DOT) {
    int i = blockIdx.x * 256 + threadIdx.x;           // over 8192*128
    int a = i >> 7, k = i & 127;
    size_t b = (size_t)a * 384 + k;
    float u0 = UV[b], u1 = UV[b+128], u2 = UV[b+256];
    float v0 = VV[b], v1 = VV[b+128], v2 = VV[b+256];
    VVN[i] = sqrtf(v0*v0 + v1*v1 + v2*v2 + EPSV);
    DOT[i] = u0*v0 + u1*v1 + u2*v2;
}

// ---------------- s,v update epilogue ----------------
__global__ void k_update(float* __restrict__ S, float* __restrict__ v,
                         const float* __restrict__ Abuf, const float* __restrict__ UV,
                         const float* __restrict__ DOT) {
    int i = blockIdx.x * 256 + threadIdx.x;           // over 8192*128
    int a = i >> 7, k = i & 127;
    size_t b = (size_t)a * 384 + k;
    float a_vv = Abuf[b], a_sv = Abuf[b+128], a_ss = Abuf[b+256];
    S[i] += a_ss + a_sv * DOT[i];
    v[b]       += a_vv * UV[b];
    v[b + 128] += a_vv * UV[b + 128];
    v[b + 256] += a_vv * UV[b + 256];
}

// ---------------- readout MLP (per atom) ----------------
__global__ __launch_bounds__(128) void k_readout(
    const float* __restrict__ S, const float* __restrict__ W1, const float* __restrict__ b1,
    const float* __restrict__ w2, const float* __restrict__ b2v, float* __restrict__ AOUT) {
    __shared__ float ss[128];
    __shared__ float red[128];
    int a = blockIdx.x, t = threadIdx.x;
    ss[t] = S[(size_t)a * 128 + t];
    __syncthreads();
    float acc = b1[t];
    #pragma unroll 8
    for (int r = 0; r < 128; r++) acc += ss[r] * W1[r*128 + t];
    float h = acc / (1.0f + __expf(-acc));
    red[t] = h * w2[t];
    __syncthreads();
    for (int s2 = 64; s2 > 0; s2 >>= 1) {
        if (t < s2) red[t] += red[t + s2];
        __syncthreads();
    }
    if (t == 0) AOUT[a] = red[0] + b2v[0];
}

// ---------------- per-molecule sum ----------------
__global__ void k_molsum(const float* __restrict__ AOUT, const int* __restrict__ mol,
                         float* __restrict__ out) {
    __shared__ float acc[N_MOL];
    int t = threadIdx.x;
    if (t < N_MOL) acc[t] = 0.f;
    __syncthreads();
    for (int i = t; i < N_ATOMS; i += 256) atomicAdd(&acc[mol[i]], AOUT[i]);
    __syncthreads();
    if (t < N_MOL) out[t] = acc[t];
}

extern "C" void kernel_launch(void* const* d_in, const int* in_sizes, int n_in,
                              void* d_out, int out_size, void* d_ws, size_t ws_size,
                              hipStream_t stream) {
    const int*   z      = (const int*)d_in[0];
    const float* pos    = (const float*)d_in[1];
    const int*   esrc   = (const int*)d_in[2];
    const int*   edst   = (const int*)d_in[3];
    const int*   mol    = (const int*)d_in[4];
    const float* embed  = (const float*)d_in[5];
    const float* msg_w1 = (const float*)d_in[6];
    const float* msg_b1 = (const float*)d_in[7];
    const float* msg_w2 = (const float*)d_in[8];
    const float* msg_b2 = (const float*)d_in[9];
    const float* rbf_w  = (const float*)d_in[10];
    const float* rbf_b  = (const float*)d_in[11];
    const float* upd_u  = (const float*)d_in[12];
    const float* upd_v  = (const float*)d_in[13];
    const float* upd_a1 = (const float*)d_in[14];
    const float* upd_a1b= (const float*)d_in[15];
    const float* upd_a2 = (const float*)d_in[16];
    const float* upd_a2b= (const float*)d_in[17];
    const float* out_w1 = (const float*)d_in[18];
    const float* out_b1 = (const float*)d_in[19];
    const float* out_w2 = (const float*)d_in[20];
    const float* out_b2 = (const float*)d_in[21];

    float* ws = (float*)d_ws;
    float* S    = ws;                ws += 1048576;     // 8192*128
    float* Va   = ws;                ws += 3145728;     // 8192*3*128
    float* Vb   = ws;                ws += 3145728;
    float* PHI  = ws;                ws += 3145728;     // shared: phi / VV / a-output (disjoint lifetimes)
    float* RBF  = ws;                ws += 5242880;     // 262144*20
    float* FC   = ws;                ws += 262144;
    float* UNIT = ws;                ws += 786432;      // 262144*3
    float* UV   = ws;                ws += 3145728;
    float* VVN  = ws;                ws += 1048576;
    float* DOT  = ws;                ws += 1048576;
    float* H    = ws;                ws += 1048576;
    float* AOUT = ws;                ws += 8192;
    int* CNT  = (int*)ws;
    int* OFF  = CNT + 8192;
    int* CUR  = OFF + 8193;
    int* EIDX = CUR + 8192;
    float* VV = PHI;   // lifetime-disjoint with phi (dead after k_aggregate) and a (born after k_vvdot)

    hipMemsetAsync(Va, 0, 3145728 * sizeof(float), stream);
    hipMemsetAsync(CNT, 0, 8192 * sizeof(int), stream);

    k_embed<<<4096, 256, 0, stream>>>(z, embed, S);
    k_edges<<<1024, 256, 0, stream>>>(pos, esrc, edst, RBF, FC, UNIT);
    k_hist<<<1024, 256, 0, stream>>>(edst, CNT);
    k_scan<<<1, 1024, 0, stream>>>(CNT, OFF, CUR);
    k_fill<<<1024, 256, 0, stream>>>(edst, CUR, EIDX);

    for (int l = 0; l < LLAYERS; l++) {
        const float* vin_ = (l & 1) ? Vb : Va;
        float*       vout_= (l & 1) ? Va : Vb;
        // phi = silu(S@w1+b1) @ w2 + b2
        k_gemm<true ><<<dim3(2, 128), 256, 0, stream>>>(S, 128, nullptr, 0, 128,
            msg_w1 + (size_t)l*128*128, msg_b1 + (size_t)l*128, H, 8192, 128, 128);
        k_gemm<false><<<dim3(6, 128), 256, 0, stream>>>(H, 128, nullptr, 0, 128,
            msg_w2 + (size_t)l*128*384, msg_b2 + (size_t)l*384, PHI, 8192, 384, 128);
        // message aggregation
        k_aggregate<<<8192, 128, 0, stream>>>(PHI, vin_, S, vout_, RBF, FC, UNIT,
            esrc, OFF, EIDX, rbf_w + (size_t)l*20*384, rbf_b + (size_t)l*384);
        // uv, vv
        k_gemm<false><<<dim3(2, 384), 256, 0, stream>>>(vout_, 128, nullptr, 0, 128,
            upd_u + (size_t)l*128*128, nullptr, UV, 24576, 128, 128);
        k_gemm<false><<<dim3(2, 384), 256, 0, stream>>>(vout_, 128, nullptr, 0, 128,
            upd_v + (size_t)l*128*128, nullptr, VV, 24576, 128, 128);
        k_vvdot<<<4096, 256, 0, stream>>>(UV, VV, VVN, DOT);
        // a = silu([S, VVN]@a1 + b1) @ a2 + b2
        k_gemm<true ><<<dim3(2, 128), 256, 0, stream>>>(S, 128, VVN, 128, 128,
            upd_a1 + (size_t)l*256*128, upd_a1b + (size_t)l*128, H, 8192, 128, 256);
        k_gemm<false><<<dim3(6, 128), 256, 0, stream>>>(H, 128, nullptr, 0, 128,
            upd_a2 + (size_t)l*128*384, upd_a2b + (size_t)l*384, PHI, 8192, 384, 128);
        k_update<<<4096, 256, 0, stream>>>(S, vout_, PHI, UV, DOT);
    }

    k_readout<<<8192, 128, 0, stream>>>(S, out_w1, out_b1, out_w2, out_b2, AOUT);
    k_molsum<<<1, 256, 0, stream>>>(AOUT, mol, (float*)d_out);
}